// Round 8
// baseline (124.519 us; speedup 1.0000x reference)
//
#include <hip/hip_runtime.h>
#include <hip/hip_bf16.h>

typedef unsigned long long u64;
typedef unsigned short u16;
typedef __attribute__((ext_vector_type(8))) short short8;
typedef __attribute__((ext_vector_type(2))) float float2_t;
typedef __attribute__((ext_vector_type(4))) float float4_t;

#define BB 8
#define SS 512
#define DD 256
#define HH 4
#define TT 20
#define BS (BB*SS)   /* 4096 tokens */

// d_out layout (floats): out[BS*DD], reg[1], Ti[BS], W[BB*HH*SS*SS]
#define REG_OFF (BS*DD)
#define TI_OFF  (REG_OFF+1)
#define W_OFF   (TI_OFF+BS)

static __device__ __forceinline__ u16 f2bf(float f) {
    __hip_bfloat16 h = __float2bfloat16(f);
    return *reinterpret_cast<u16*>(&h);
}

// ===================== Kernel G: gate MLP -> Ti =====================
// 1024 blocks x 256 thr; wave = 1 token (4 tokens/block)
__global__ __launch_bounds__(256) void k_gate(
    const float* __restrict__ x,
    const float* __restrict__ Wg1, const float* __restrict__ bg1,
    const float* __restrict__ Wg2, const float* __restrict__ bg2,
    float* __restrict__ ti_out)
{
    const int tid  = threadIdx.x;
    const int tok  = blockIdx.x * 4 + (tid >> 6);
    const int lane = tid & 63;
    const int c    = lane & 31;
    const int half = lane >> 5;

    const float* xr = x + (size_t)tok*DD + half*128;
    const float* wg = Wg1 + (size_t)half*128*32 + c;
    float acc = 0.f;
    #pragma unroll 4
    for (int i = 0; i < 32; ++i) {
        float4_t xv = *reinterpret_cast<const float4_t*>(xr + i*4);
        acc += xv.x * wg[(i*4+0)*32] + xv.y * wg[(i*4+1)*32]
             + xv.z * wg[(i*4+2)*32] + xv.w * wg[(i*4+3)*32];
    }
    acc += __shfl_xor(acc, 32, 64);   // combine K-halves (same c)
    acc += bg1[c];
    float hrelu = acc > 0.f ? acc : 0.f;
    float term  = hrelu * Wg2[c];
    #pragma unroll
    for (int msk = 16; msk >= 1; msk >>= 1) term += __shfl_xor(term, msk, 64);
    if (lane == 0) {
        float g  = term + bg2[0];
        float sg = 1.f / (1.f + expf(-g));
        int ti = (int)ceilf(sg * (float)TT);
        ti = ti < 1 ? 1 : (ti > TT ? TT : ti);
        ti_out[tok] = (float)ti;
    }
}

// ===================== Kernel A: one projection + LIF (full-K per thread) ==========
// grid (512, 3) x 256 thr: bx = 8-token tile, by = projection (0=q,1=k,2=v)
// GEMM: thread (c = tid&63, tg = tid>>6): 4 cols x 2 tokens (tg*2..), K=256 in-thread.
//   Wave = token group -> xt read is wave-uniform broadcast.
// Exchange via LDS, then LIF with col = tid (h = tid>>6, lane = channel).
__global__ __launch_bounds__(256) void k_proj_lif(
    const float* __restrict__ x, const float* __restrict__ Wq,
    const float* __restrict__ Wk, const float* __restrict__ Wv,
    const float* __restrict__ aq, const float* __restrict__ bq_,
    const float* __restrict__ ak, const float* __restrict__ bk_,
    const float* __restrict__ av, const float* __restrict__ bv_,
    const float* __restrict__ ti_in,
    u64* __restrict__ qpack, u64* __restrict__ kpack,
    u16* __restrict__ vmbT)
{
    __shared__ __align__(16) union {
        float xt[DD][8];    // 8 KB: x transposed (row r, token m)
        float ax[8][DD];    // 8 KB: acc exchange (token m, col)
    } sm;
    __shared__ int til[8];
    const int tid  = threadIdx.x;
    const int proj = blockIdx.y;
    const int tok0 = blockIdx.x * 8;

    #pragma unroll
    for (int m = 0; m < 8; ++m) sm.xt[tid][m] = x[(size_t)(tok0+m)*DD + tid];
    if (tid < 8) til[tid] = (int)ti_in[tok0 + tid];
    __syncthreads();

    const float* W    = proj == 0 ? Wq  : (proj == 1 ? Wk  : Wv);
    const float alpha = proj == 0 ? *aq : (proj == 1 ? *ak : *av);
    const float beta  = proj == 0 ? *bq_: (proj == 1 ? *bk_: *bv_);

    const int c  = tid & 63;    // col quad
    const int tg = tid >> 6;    // token pair == wave

    float4_t acc[2];
    acc[0] = (float4_t){0.f, 0.f, 0.f, 0.f};
    acc[1] = (float4_t){0.f, 0.f, 0.f, 0.f};

    const float* Wp = W + c*4;
    #pragma unroll 8
    for (int r = 0; r < DD; ++r) {
        float4_t wf = *reinterpret_cast<const float4_t*>(Wp + (size_t)r*DD);
        float2_t xv = *reinterpret_cast<const float2_t*>(&sm.xt[r][tg*2]);
        acc[0] += wf*xv.x; acc[1] += wf*xv.y;
    }
    __syncthreads();   // xt dead; union overwrite safe
    *reinterpret_cast<float4_t*>(&sm.ax[tg*2    ][c*4]) = acc[0];
    *reinterpret_cast<float4_t*>(&sm.ax[tg*2 + 1][c*4]) = acc[1];
    __syncthreads();

    float val[8];
    #pragma unroll
    for (int m = 0; m < 8; ++m) val[m] = sm.ax[m][tid];

    const int lane = tid & 63;
    const int h    = tid >> 6;
    if (proj < 2) {
        u64* pack = (proj == 0) ? qpack : kpack;
        for (int m = 0; m < 8; ++m) {
            const int ti = til[m];
            float vv = 0.f, cur = 0.f;
            u64 myw = 0ull;
            #pragma unroll
            for (int t = 0; t < TT; ++t) {
                cur = alpha*cur + val[m];
                vv  = beta*vv + cur;
                bool s = (vv >= 1.f);
                u64 bal = __ballot(s);
                if (s) vv = 0.f;
                if (lane == t && t < ti) myw = bal;
            }
            if (lane < TT)
                pack[((size_t)(tok0+m)*HH + h)*TT + lane] = myw;
        }
    } else {
        u16 tmp[8];
        for (int m = 0; m < 8; ++m) {
            const int ti = til[m];
            float vv = 0.f, cur = 0.f, cnt = 0.f;
            #pragma unroll
            for (int t = 0; t < TT; ++t) {
                cur = alpha*cur + val[m];
                vv  = beta*vv + cur;
                bool s = (vv >= 1.f);
                if (s) { vv = 0.f; if (t < ti) cnt += 1.f; }
            }
            tmp[m] = f2bf(cnt * 0.05f);
        }
        // transposed store: vmbT[ch][tok]
        *reinterpret_cast<short8*>(&vmbT[(size_t)tid*BS + tok0]) =
            *reinterpret_cast<short8*>(&tmp[0]);
    }
}

// ===================== Kernel C: popcount scores + softmax + W + PV (MFMA) ===========
__global__ __launch_bounds__(256) void k_attn(
    const u64* __restrict__ qpack, const u64* __restrict__ kpack,
    const u16* __restrict__ vmbT,
    float* __restrict__ Wout, float* __restrict__ attn)
{
    __shared__ u64 ql[16][TT];                 // 2.5 KB
    __shared__ __align__(16) u16 CP[16*SS];    // 16 KB: counts, then P (bf16, swizzled)
    const int tid  = threadIdx.x;
    const int tile = blockIdx.x & 31;
    const int h    = (blockIdx.x >> 5) & 3;
    const int b    = blockIdx.x >> 7;
    const int i0   = tile * 16;
    const int lane = tid & 63, wv = tid >> 6;

    for (int idx = tid; idx < 16*TT; idx += 256) {
        int i = idx / TT, t = idx - i*TT;
        ql[i][t] = qpack[((size_t)(b*SS + i0 + i)*HH + h)*TT + t];
    }

    u64 kr0[TT], kr1[TT];
    {
        const u64* kp0 = &kpack[((size_t)(b*SS + tid      )*HH + h)*TT];
        const u64* kp1 = &kpack[((size_t)(b*SS + tid + 256)*HH + h)*TT];
        #pragma unroll
        for (int t = 0; t < TT; ++t) { kr0[t] = kp0[t]; kr1[t] = kp1[t]; }
    }
    __syncthreads();

    // scores as integer counts
    for (int i = 0; i < 16; ++i) {
        int c0 = 0, c1 = 0;
        #pragma unroll
        for (int t = 0; t < TT; ++t) {
            u64 q = ql[i][t];
            c0 += __popcll(q & kr0[t]);
            c1 += __popcll(q & kr1[t]);
        }
        CP[i*SS + tid]       = (u16)c0;
        CP[i*SS + tid + 256] = (u16)c1;
    }
    __syncthreads();

    // softmax per row (wave wv owns rows wv*4..wv*4+3); write W f32, P bf16 swizzled
    for (int rr = 0; rr < 4; ++rr) {
        const int i = wv*4 + rr;
        float sv[8];
        float m = -1e30f;
        #pragma unroll
        for (int k2 = 0; k2 < 8; ++k2) {
            sv[k2] = (float)CP[i*SS + lane + 64*k2] * 0.125f;
            m = fmaxf(m, sv[k2]);
        }
        #pragma unroll
        for (int msk = 32; msk >= 1; msk >>= 1) m = fmaxf(m, __shfl_xor(m, msk, 64));
        float sum = 0.f;
        #pragma unroll
        for (int k2 = 0; k2 < 8; ++k2) { sv[k2] = expf(sv[k2] - m); sum += sv[k2]; }
        #pragma unroll
        for (int msk = 32; msk >= 1; msk >>= 1) sum += __shfl_xor(sum, msk, 64);
        float inv = 1.f / sum;
        size_t wbase = ((size_t)((b*HH + h)*SS) + i0 + i) * SS;
        #pragma unroll
        for (int k2 = 0; k2 < 8; ++k2) {
            int j = lane + 64*k2;
            float wval = sv[k2] * inv;
            Wout[wbase + j] = wval;
            CP[(i*SS + j) ^ ((i & 7) << 3)] = f2bf(wval);
        }
    }
    __syncthreads();

    // PV via mfma_f32_16x16x32_bf16: out tile 16 x 64, wave wv owns n-tile of 16
    const int n0 = wv * 16;
    const int mr = lane & 15;    // A row / B col / D col
    const int g  = lane >> 4;    // k-group
    float4_t acc = {0.f, 0.f, 0.f, 0.f};
    const u16* vbT = vmbT + (size_t)(h*64 + n0 + mr)*BS + b*SS;
    for (int ks = 0; ks < 16; ++ks) {
        int k = ks*32 + g*8;
        int aidx = (mr*SS + k) ^ ((mr & 7) << 3);
        short8 afrag = *reinterpret_cast<const short8*>(&CP[aidx]);
        short8 bfrag = *reinterpret_cast<const short8*>(vbT + k);
        acc = __builtin_amdgcn_mfma_f32_16x16x32_bf16(afrag, bfrag, acc, 0, 0, 0);
    }
    #pragma unroll
    for (int r = 0; r < 4; ++r) {
        int row = g*4 + r;   // D: row=(lane>>4)*4+reg, col=lane&15
        attn[(size_t)(b*SS + i0 + row)*DD + h*64 + n0 + mr] = acc[r];
    }
}

// ===================== Kernel D: out = attn @ Wo + bo (full-K per thread) + reg =====
__global__ __launch_bounds__(256) void k_outproj(
    const float* __restrict__ attn, const float* __restrict__ Wo,
    const float* __restrict__ bo, const float* __restrict__ ti,
    float* __restrict__ out)
{
    __shared__ __align__(16) union {
        float xt[DD][8];
        float ax[8][DD];
    } sm;
    __shared__ float ps[4];
    const int tid  = threadIdx.x;
    const int tok0 = blockIdx.x * 8;

    #pragma unroll
    for (int m = 0; m < 8; ++m) sm.xt[tid][m] = attn[(size_t)(tok0+m)*DD + tid];
    __syncthreads();

    const int c  = tid & 63;
    const int tg = tid >> 6;

    float4_t acc[2];
    acc[0] = (float4_t){0.f, 0.f, 0.f, 0.f};
    acc[1] = (float4_t){0.f, 0.f, 0.f, 0.f};
    const float* Wp = Wo + c*4;
    #pragma unroll 8
    for (int r = 0; r < DD; ++r) {
        float4_t wf = *reinterpret_cast<const float4_t*>(Wp + (size_t)r*DD);
        float2_t xv = *reinterpret_cast<const float2_t*>(&sm.xt[r][tg*2]);
        acc[0] += wf*xv.x; acc[1] += wf*xv.y;
    }
    __syncthreads();
    *reinterpret_cast<float4_t*>(&sm.ax[tg*2    ][c*4]) = acc[0];
    *reinterpret_cast<float4_t*>(&sm.ax[tg*2 + 1][c*4]) = acc[1];
    __syncthreads();

    float bb = bo[tid];
    #pragma unroll
    for (int m = 0; m < 8; ++m)
        out[(size_t)(tok0+m)*DD + tid] = sm.ax[m][tid] + bb;

    if (blockIdx.x == 0) {   // fold reg = 1e-3 * mean(Ti)
        float s = 0.f;
        for (int m = 0; m < 16; ++m) s += ti[m*256 + tid];
        #pragma unroll
        for (int msk = 32; msk >= 1; msk >>= 1) s += __shfl_xor(s, msk, 64);
        if ((tid & 63) == 0) ps[tid >> 6] = s;
        __syncthreads();
        if (tid == 0) out[REG_OFF] = 1e-3f * (ps[0]+ps[1]+ps[2]+ps[3]) / 4096.f;
    }
}

extern "C" void kernel_launch(void* const* d_in, const int* in_sizes, int n_in,
                              void* d_out, int out_size, void* d_ws, size_t ws_size,
                              hipStream_t stream)
{
    (void)in_sizes; (void)n_in; (void)out_size; (void)ws_size;
    const float* x   = (const float*)d_in[0];
    const float* Wq  = (const float*)d_in[1];
    const float* Wk  = (const float*)d_in[2];
    const float* Wv  = (const float*)d_in[3];
    const float* Wo  = (const float*)d_in[4];
    const float* bo  = (const float*)d_in[5];
    const float* Wg1 = (const float*)d_in[6];
    const float* bg1 = (const float*)d_in[7];
    const float* Wg2 = (const float*)d_in[8];
    const float* bg2 = (const float*)d_in[9];
    const float* aq  = (const float*)d_in[10];
    const float* bq  = (const float*)d_in[11];
    const float* ak  = (const float*)d_in[12];
    const float* bk  = (const float*)d_in[13];
    const float* av  = (const float*)d_in[14];
    const float* bv  = (const float*)d_in[15];
    float* out = (float*)d_out;

    u64* qp = (u64*)d_ws;
    u64* kp = qp + (size_t)BS*HH*TT;
    u16* vmbT = (u16*)(kp + (size_t)BS*HH*TT);
    float* attnbuf = (float*)(vmbT + (size_t)BS*DD);

    k_gate<<<1024, 256, 0, stream>>>(x, Wg1, bg1, Wg2, bg2, out + TI_OFF);
    dim3 gproj(512, 3);
    k_proj_lif<<<gproj, 256, 0, stream>>>(x, Wq, Wk, Wv,
        aq, bq, ak, bk, av, bv, out + TI_OFF, qp, kp, vmbT);
    k_attn<<<1024, 256, 0, stream>>>(qp, kp, vmbT, out + W_OFF, attnbuf);
    k_outproj<<<512, 256, 0, stream>>>(attnbuf, Wo, bo, out + TI_OFF, out);
}

// Round 11
// 104.005 us; speedup vs baseline: 1.1972x; 1.1972x over previous
//
#include <hip/hip_runtime.h>
#include <hip/hip_bf16.h>

typedef unsigned long long u64;
typedef unsigned short u16;
typedef __attribute__((ext_vector_type(8))) short short8;
typedef __attribute__((ext_vector_type(4))) float float4_t;

#define BB 8
#define SS 512
#define DD 256
#define HH 4
#define TT 20
#define BS (BB*SS)   /* 4096 tokens */

// d_out layout (floats): out[BS*DD], reg[1], Ti[BS], W[BB*HH*SS*SS]
#define REG_OFF (BS*DD)
#define TI_OFF  (REG_OFF+1)
#define W_OFF   (TI_OFF+BS)

static __device__ __forceinline__ u16 f2bf(float f) {
    __hip_bfloat16 h = __float2bfloat16(f);
    return *reinterpret_cast<u16*>(&h);
}

// ===================== Kernel G: gate MLP -> Ti =====================
// 1024 blocks x 256 thr; wave = 1 token (4 tokens/block)
__global__ __launch_bounds__(256) void k_gate(
    const float* __restrict__ x,
    const float* __restrict__ Wg1, const float* __restrict__ bg1,
    const float* __restrict__ Wg2, const float* __restrict__ bg2,
    float* __restrict__ ti_out)
{
    const int tid  = threadIdx.x;
    const int tok  = blockIdx.x * 4 + (tid >> 6);
    const int lane = tid & 63;
    const int c    = lane & 31;
    const int half = lane >> 5;

    const float* xr = x + (size_t)tok*DD + half*128;
    const float* wg = Wg1 + (size_t)half*128*32 + c;
    float acc = 0.f;
    #pragma unroll 4
    for (int i = 0; i < 32; ++i) {
        float4_t xv = *reinterpret_cast<const float4_t*>(xr + i*4);
        acc += xv.x * wg[(i*4+0)*32] + xv.y * wg[(i*4+1)*32]
             + xv.z * wg[(i*4+2)*32] + xv.w * wg[(i*4+3)*32];
    }
    acc += __shfl_xor(acc, 32, 64);   // combine K-halves (same c)
    acc += bg1[c];
    float hrelu = acc > 0.f ? acc : 0.f;
    float term  = hrelu * Wg2[c];
    #pragma unroll
    for (int msk = 16; msk >= 1; msk >>= 1) term += __shfl_xor(term, msk, 64);
    if (lane == 0) {
        float g  = term + bg2[0];
        float sg = 1.f / (1.f + expf(-g));
        int ti = (int)ceilf(sg * (float)TT);
        ti = ti < 1 ? 1 : (ti > TT ? TT : ti);
        ti_out[tok] = (float)ti;
    }
}

// ===================== prep: Wo -> transposed bf16 [n][k] =====================
// 32 blocks x 256 thr
__global__ __launch_bounds__(256) void k_prep_wo(
    const float* __restrict__ Wo, u16* __restrict__ WoT)
{
    const int e  = blockIdx.x * 256 + threadIdx.x;   // [0, 8192)
    const int n  = e & 255;
    const int k0 = (e >> 8) * 8;
    u16 a[8];
    #pragma unroll
    for (int j = 0; j < 8; ++j) a[j] = f2bf(Wo[(size_t)(k0+j)*DD + n]);
    *reinterpret_cast<short8*>(&WoT[(size_t)n*DD + k0]) = *reinterpret_cast<short8*>(a);
}

// ===================== Kernel A: one projection + LIF (split-K, R5-proven) ==========
// grid (512, 3): bx = token tile (8 tokens), by = projection (0=q,1=k,2=v)
__global__ __launch_bounds__(256) void k_proj_lif(
    const float* __restrict__ x, const float* __restrict__ Wq,
    const float* __restrict__ Wk, const float* __restrict__ Wv,
    const float* __restrict__ aq, const float* __restrict__ bq_,
    const float* __restrict__ ak, const float* __restrict__ bk_,
    const float* __restrict__ av, const float* __restrict__ bv_,
    const float* __restrict__ ti_in,
    u64* __restrict__ qpack, u64* __restrict__ kpack,
    u16* __restrict__ vmbT)
{
    __shared__ __align__(16) union {
        float xt[DD][8];        // 8 KB: x transposed (row r, token m)
        float red[4][8][DD];    // 32 KB: per-wave partial sums
    } sm;
    __shared__ int til[8];
    const int tid  = threadIdx.x;
    const int proj = blockIdx.y;
    const int tok0 = blockIdx.x * 8;
    const int w = tid >> 6, l = tid & 63;

    #pragma unroll
    for (int m = 0; m < 8; ++m) sm.xt[tid][m] = x[(size_t)(tok0+m)*DD + tid];
    if (tid < 8) til[tid] = (int)ti_in[tok0 + tid];
    __syncthreads();

    const float* W    = proj == 0 ? Wq  : (proj == 1 ? Wk  : Wv);
    const float alpha = proj == 0 ? *aq : (proj == 1 ? *ak : *av);
    const float beta  = proj == 0 ? *bq_: (proj == 1 ? *bk_: *bv_);

    float4_t a[8];
    #pragma unroll
    for (int i = 0; i < 8; ++i) a[i] = (float4_t){0.f, 0.f, 0.f, 0.f};

    const float* Wp = W + (size_t)(w*64)*DD + l*4;
    #pragma unroll 4
    for (int r0 = 0; r0 < 64; ++r0) {
        float4_t wf = *reinterpret_cast<const float4_t*>(Wp + (size_t)r0*DD);
        int r = (w << 6) + r0;
        float4_t x0 = *reinterpret_cast<const float4_t*>(&sm.xt[r][0]);
        float4_t x1 = *reinterpret_cast<const float4_t*>(&sm.xt[r][4]);
        a[0] += wf*x0.x; a[1] += wf*x0.y; a[2] += wf*x0.z; a[3] += wf*x0.w;
        a[4] += wf*x1.x; a[5] += wf*x1.y; a[6] += wf*x1.z; a[7] += wf*x1.w;
    }
    __syncthreads();   // xt dead; safe to overwrite via union
    #pragma unroll
    for (int i = 0; i < 8; ++i)
        *reinterpret_cast<float4_t*>(&sm.red[w][i][l*4]) = a[i];
    __syncthreads();

    float val[8];
    #pragma unroll
    for (int i = 0; i < 8; ++i)
        val[i] = (sm.red[0][i][tid] + sm.red[1][i][tid])
               + (sm.red[2][i][tid] + sm.red[3][i][tid]);

    const int h = w;   // col = tid -> head = tid>>6, channel = lane
    if (proj < 2) {
        u64* pack = (proj == 0) ? qpack : kpack;
        for (int i = 0; i < 8; ++i) {
            const int ti = til[i];
            float vv = 0.f, cur = 0.f;
            u64 myw = 0ull;
            #pragma unroll
            for (int t = 0; t < TT; ++t) {
                cur = alpha*cur + val[i];
                vv  = beta*vv + cur;
                bool s = (vv >= 1.f);
                u64 bal = __ballot(s);
                if (s) vv = 0.f;
                if (l == t && t < ti) myw = bal;
            }
            if (l < TT)
                pack[((size_t)(tok0+i)*HH + h)*TT + l] = myw;
        }
    } else {
        u16 tmp[8];
        for (int i = 0; i < 8; ++i) {
            const int ti = til[i];
            float vv = 0.f, cur = 0.f, cnt = 0.f;
            #pragma unroll
            for (int t = 0; t < TT; ++t) {
                cur = alpha*cur + val[i];
                vv  = beta*vv + cur;
                bool s = (vv >= 1.f);
                if (s) { vv = 0.f; if (t < ti) cnt += 1.f; }
            }
            tmp[i] = f2bf(cnt * 0.05f);
        }
        // transposed store: vmbT[ch][tok], 8 consecutive tokens = 16B
        *reinterpret_cast<short8*>(&vmbT[(size_t)tid*BS + tok0]) =
            *reinterpret_cast<short8*>(tmp);
    }
}

// ===================== Kernel C: popcount scores + softmax + W + PV (MFMA) ===========
__global__ __launch_bounds__(256) void k_attn(
    const u64* __restrict__ qpack, const u64* __restrict__ kpack,
    const u16* __restrict__ vmbT,
    float* __restrict__ Wout, u16* __restrict__ attnb)
{
    __shared__ u64 ql[16][TT];                 // 2.5 KB
    __shared__ __align__(16) u16 CP[16*SS];    // 16 KB
    const int tid  = threadIdx.x;
    const int tile = blockIdx.x & 31;
    const int h    = (blockIdx.x >> 5) & 3;
    const int b    = blockIdx.x >> 7;
    const int i0   = tile * 16;
    const int lane = tid & 63, wv = tid >> 6;

    for (int idx = tid; idx < 16*TT; idx += 256) {
        int i = idx / TT, t = idx - i*TT;
        ql[i][t] = qpack[((size_t)(b*SS + i0 + i)*HH + h)*TT + t];
    }

    u64 kr0[TT], kr1[TT];
    {
        const u64* kp0 = &kpack[((size_t)(b*SS + tid      )*HH + h)*TT];
        const u64* kp1 = &kpack[((size_t)(b*SS + tid + 256)*HH + h)*TT];
        #pragma unroll
        for (int t = 0; t < TT; ++t) { kr0[t] = kp0[t]; kr1[t] = kp1[t]; }
    }
    __syncthreads();

    for (int i = 0; i < 16; ++i) {
        int c0 = 0, c1 = 0;
        #pragma unroll
        for (int t = 0; t < TT; ++t) {
            u64 q = ql[i][t];
            c0 += __popcll(q & kr0[t]);
            c1 += __popcll(q & kr1[t]);
        }
        CP[i*SS + tid]       = (u16)c0;
        CP[i*SS + tid + 256] = (u16)c1;
    }
    __syncthreads();

    for (int rr = 0; rr < 4; ++rr) {
        const int i = wv*4 + rr;
        float sv[8];
        float m = -1e30f;
        #pragma unroll
        for (int k2 = 0; k2 < 8; ++k2) {
            sv[k2] = (float)CP[i*SS + lane + 64*k2] * 0.125f;
            m = fmaxf(m, sv[k2]);
        }
        #pragma unroll
        for (int msk = 32; msk >= 1; msk >>= 1) m = fmaxf(m, __shfl_xor(m, msk, 64));
        float sum = 0.f;
        #pragma unroll
        for (int k2 = 0; k2 < 8; ++k2) { sv[k2] = expf(sv[k2] - m); sum += sv[k2]; }
        #pragma unroll
        for (int msk = 32; msk >= 1; msk >>= 1) sum += __shfl_xor(sum, msk, 64);
        float inv = 1.f / sum;
        size_t wbase = ((size_t)((b*HH + h)*SS) + i0 + i) * SS;
        #pragma unroll
        for (int k2 = 0; k2 < 8; ++k2) {
            int j = lane + 64*k2;
            float wval = sv[k2] * inv;
            Wout[wbase + j] = wval;
            CP[(i*SS + j) ^ ((i & 7) << 3)] = f2bf(wval);
        }
    }
    __syncthreads();

    const int n0 = wv * 16;
    const int mr = lane & 15;
    const int g  = lane >> 4;
    float4_t acc = {0.f, 0.f, 0.f, 0.f};
    const u16* vbT = vmbT + (size_t)(h*64 + n0 + mr)*BS + b*SS;
    for (int ks = 0; ks < 16; ++ks) {
        int k = ks*32 + g*8;
        int aidx = (mr*SS + k) ^ ((mr & 7) << 3);
        short8 afrag = *reinterpret_cast<const short8*>(&CP[aidx]);
        short8 bfrag = *reinterpret_cast<const short8*>(vbT + k);
        acc = __builtin_amdgcn_mfma_f32_16x16x32_bf16(afrag, bfrag, acc, 0, 0, 0);
    }
    #pragma unroll
    for (int r = 0; r < 4; ++r) {
        int row = g*4 + r;
        attnb[(size_t)(b*SS + i0 + row)*DD + h*64 + n0 + mr] = f2bf(acc[r]);
    }
}

// ===================== Kernel D: out = attn @ Wo + bo via MFMA bf16 + reg =====
// 256 blocks x 256 thr: 16 tokens/block, wave = n-quarter.
__global__ __launch_bounds__(256) void k_outproj(
    const u16* __restrict__ attnb, const u16* __restrict__ WoT,
    const float* __restrict__ bo, const float* __restrict__ ti,
    float* __restrict__ out)
{
    __shared__ float ps[4];
    const int tid  = threadIdx.x;
    const int tok0 = blockIdx.x * 16;
    const int lane = tid & 63;
    const int wv   = tid >> 6;
    const int mr   = lane & 15;
    const int g    = lane >> 4;

    float4_t acc[4];
    #pragma unroll
    for (int f = 0; f < 4; ++f) acc[f] = (float4_t){0.f, 0.f, 0.f, 0.f};

    const size_t arow = (size_t)(tok0 + mr)*DD + g*8;
    #pragma unroll 4
    for (int ks = 0; ks < 8; ++ks) {
        const int k = ks*32;
        short8 a = *reinterpret_cast<const short8*>(&attnb[arow + k]);
        #pragma unroll
        for (int f = 0; f < 4; ++f) {
            const size_t brow = (size_t)(wv*64 + f*16 + mr)*DD + k + g*8;
            short8 b = *reinterpret_cast<const short8*>(&WoT[brow]);
            acc[f] = __builtin_amdgcn_mfma_f32_16x16x32_bf16(a, b, acc[f], 0, 0, 0);
        }
    }
    #pragma unroll
    for (int f = 0; f < 4; ++f) {
        const int col = wv*64 + f*16 + mr;
        const float bb = bo[col];
        #pragma unroll
        for (int r = 0; r < 4; ++r)
            out[(size_t)(tok0 + g*4 + r)*DD + col] = acc[f][r] + bb;
    }

    if (blockIdx.x == 0) {
        float s = 0.f;
        for (int m = 0; m < 16; ++m) s += ti[m*256 + tid];
        #pragma unroll
        for (int msk = 32; msk >= 1; msk >>= 1) s += __shfl_xor(s, msk, 64);
        if ((tid & 63) == 0) ps[tid >> 6] = s;
        __syncthreads();
        if (tid == 0) out[REG_OFF] = 1e-3f * (ps[0]+ps[1]+ps[2]+ps[3]) / 4096.f;
    }
}

extern "C" void kernel_launch(void* const* d_in, const int* in_sizes, int n_in,
                              void* d_out, int out_size, void* d_ws, size_t ws_size,
                              hipStream_t stream)
{
    (void)in_sizes; (void)n_in; (void)out_size; (void)ws_size;
    const float* x   = (const float*)d_in[0];
    const float* Wq  = (const float*)d_in[1];
    const float* Wk  = (const float*)d_in[2];
    const float* Wv  = (const float*)d_in[3];
    const float* Wo  = (const float*)d_in[4];
    const float* bo  = (const float*)d_in[5];
    const float* Wg1 = (const float*)d_in[6];
    const float* bg1 = (const float*)d_in[7];
    const float* Wg2 = (const float*)d_in[8];
    const float* bg2 = (const float*)d_in[9];
    const float* aq  = (const float*)d_in[10];
    const float* bq  = (const float*)d_in[11];
    const float* ak  = (const float*)d_in[12];
    const float* bk  = (const float*)d_in[13];
    const float* av  = (const float*)d_in[14];
    const float* bv  = (const float*)d_in[15];
    float* out = (float*)d_out;

    u64* qp    = (u64*)d_ws;                       // 2.62 MB
    u64* kp    = qp + (size_t)BS*HH*TT;            // 2.62 MB
    u16* vmbT  = (u16*)(kp + (size_t)BS*HH*TT);    // 2 MB
    u16* attnb = vmbT + (size_t)BS*DD;             // 2 MB
    u16* WoT   = attnb + (size_t)BS*DD;            // 128 KB

    k_gate<<<1024, 256, 0, stream>>>(x, Wg1, bg1, Wg2, bg2, out + TI_OFF);
    k_prep_wo<<<32, 256, 0, stream>>>(Wo, WoT);
    dim3 gproj(512, 3);
    k_proj_lif<<<gproj, 256, 0, stream>>>(x, Wq, Wk, Wv,
        aq, bq, ak, bk, av, bv, out + TI_OFF, qp, kp, vmbT);
    k_attn<<<1024, 256, 0, stream>>>(qp, kp, vmbT, out + W_OFF, attnb);
    k_outproj<<<256, 256, 0, stream>>>(attnb, WoT, bo, out + TI_OFF, out);
}

// Round 13
// 103.299 us; speedup vs baseline: 1.2054x; 1.0068x over previous
//
#include <hip/hip_runtime.h>
#include <hip/hip_bf16.h>

typedef unsigned long long u64;
typedef unsigned short u16;
typedef __attribute__((ext_vector_type(8))) short short8;
typedef __attribute__((ext_vector_type(4))) unsigned short ushort4_t;
typedef __attribute__((ext_vector_type(4))) float float4_t;

#define BB 8
#define SS 512
#define DD 256
#define HH 4
#define TT 20
#define BS (BB*SS)   /* 4096 tokens */

// d_out layout (floats): out[BS*DD], reg[1], Ti[BS], W[BB*HH*SS*SS]
#define REG_OFF (BS*DD)
#define TI_OFF  (REG_OFF+1)
#define W_OFF   (TI_OFF+BS)

static __device__ __forceinline__ u16 f2bf(float f) {
    __hip_bfloat16 h = __float2bfloat16(f);
    return *reinterpret_cast<u16*>(&h);
}

// ===================== Kernel G: gate MLP -> Ti =====================
// 1024 blocks x 256 thr; wave = 1 token (4 tokens/block)
__global__ __launch_bounds__(256) void k_gate(
    const float* __restrict__ x,
    const float* __restrict__ Wg1, const float* __restrict__ bg1,
    const float* __restrict__ Wg2, const float* __restrict__ bg2,
    float* __restrict__ ti_out)
{
    const int tid  = threadIdx.x;
    const int tok  = blockIdx.x * 4 + (tid >> 6);
    const int lane = tid & 63;
    const int c    = lane & 31;
    const int half = lane >> 5;

    const float* xr = x + (size_t)tok*DD + half*128;
    const float* wg = Wg1 + (size_t)half*128*32 + c;
    float acc = 0.f;
    #pragma unroll 4
    for (int i = 0; i < 32; ++i) {
        float4_t xv = *reinterpret_cast<const float4_t*>(xr + i*4);
        acc += xv.x * wg[(i*4+0)*32] + xv.y * wg[(i*4+1)*32]
             + xv.z * wg[(i*4+2)*32] + xv.w * wg[(i*4+3)*32];
    }
    acc += __shfl_xor(acc, 32, 64);   // combine K-halves (same c)
    acc += bg1[c];
    float hrelu = acc > 0.f ? acc : 0.f;
    float term  = hrelu * Wg2[c];
    #pragma unroll
    for (int msk = 16; msk >= 1; msk >>= 1) term += __shfl_xor(term, msk, 64);
    if (lane == 0) {
        float g  = term + bg2[0];
        float sg = 1.f / (1.f + expf(-g));
        int ti = (int)ceilf(sg * (float)TT);
        ti = ti < 1 ? 1 : (ti > TT ? TT : ti);
        ti_out[tok] = (float)ti;
    }
}

// ===================== prep: Wo -> transposed bf16 [n][k] =====================
__global__ __launch_bounds__(256) void k_prep_wo(
    const float* __restrict__ Wo, u16* __restrict__ WoT)
{
    const int e  = blockIdx.x * 256 + threadIdx.x;   // [0, 8192)
    const int n  = e & 255;
    const int k0 = (e >> 8) * 8;
    u16 a[8];
    #pragma unroll
    for (int j = 0; j < 8; ++j) a[j] = f2bf(Wo[(size_t)(k0+j)*DD + n]);
    *reinterpret_cast<short8*>(&WoT[(size_t)n*DD + k0]) = *reinterpret_cast<short8*>(a);
}

// ===================== Kernel A: one projection + LIF (split-K f32, two-phase) =====
// grid (512, 3): bx = token tile (8 tokens), by = projection (0=q,1=k,2=v)
// GEMM identical to the R11-proven kernel; only the LDS exchange is split into
// two 4-token phases so the union drops 32 KB -> 16 KB (occupancy 31% -> ~70%).
__global__ __launch_bounds__(256) void k_proj_lif(
    const float* __restrict__ x, const float* __restrict__ Wq,
    const float* __restrict__ Wk, const float* __restrict__ Wv,
    const float* __restrict__ aq, const float* __restrict__ bq_,
    const float* __restrict__ ak, const float* __restrict__ bk_,
    const float* __restrict__ av, const float* __restrict__ bv_,
    const float* __restrict__ ti_in,
    u64* __restrict__ qpack, u64* __restrict__ kpack,
    u16* __restrict__ vmbT)
{
    __shared__ __align__(16) union {
        float xt[DD][8];        // 8 KB: x transposed (row r, token m)
        float red[4][4][DD];    // 16 KB: per-wave partials, 4 tokens/phase
    } sm;
    __shared__ int til[8];
    const int tid  = threadIdx.x;
    const int proj = blockIdx.y;
    const int tok0 = blockIdx.x * 8;
    const int w = tid >> 6, l = tid & 63;

    #pragma unroll
    for (int m = 0; m < 8; ++m) sm.xt[tid][m] = x[(size_t)(tok0+m)*DD + tid];
    if (tid < 8) til[tid] = (int)ti_in[tok0 + tid];
    __syncthreads();

    const float* W    = proj == 0 ? Wq  : (proj == 1 ? Wk  : Wv);
    const float alpha = proj == 0 ? *aq : (proj == 1 ? *ak : *av);
    const float beta  = proj == 0 ? *bq_: (proj == 1 ? *bk_: *bv_);

    float4_t a[8];
    #pragma unroll
    for (int i = 0; i < 8; ++i) a[i] = (float4_t){0.f, 0.f, 0.f, 0.f};

    const float* Wp = W + (size_t)(w*64)*DD + l*4;
    #pragma unroll 4
    for (int r0 = 0; r0 < 64; ++r0) {
        float4_t wf = *reinterpret_cast<const float4_t*>(Wp + (size_t)r0*DD);
        int r = (w << 6) + r0;
        float4_t x0 = *reinterpret_cast<const float4_t*>(&sm.xt[r][0]);
        float4_t x1 = *reinterpret_cast<const float4_t*>(&sm.xt[r][4]);
        a[0] += wf*x0.x; a[1] += wf*x0.y; a[2] += wf*x0.z; a[3] += wf*x0.w;
        a[4] += wf*x1.x; a[5] += wf*x1.y; a[6] += wf*x1.z; a[7] += wf*x1.w;
    }

    const int h = w;
    u64* pack = (proj == 0) ? qpack : kpack;

    for (int ph = 0; ph < 2; ++ph) {
        __syncthreads();   // ph0: xt dead; ph1: red reads done
        #pragma unroll
        for (int i = 0; i < 4; ++i)
            *reinterpret_cast<float4_t*>(&sm.red[w][i][l*4]) = a[ph*4 + i];
        __syncthreads();

        float val[4];
        #pragma unroll
        for (int i = 0; i < 4; ++i)
            val[i] = (sm.red[0][i][tid] + sm.red[1][i][tid])
                   + (sm.red[2][i][tid] + sm.red[3][i][tid]);

        if (proj < 2) {
            for (int i = 0; i < 4; ++i) {
                const int m  = ph*4 + i;
                const int ti = til[m];
                float vv = 0.f, cur = 0.f;
                u64 myw = 0ull;
                #pragma unroll
                for (int t = 0; t < TT; ++t) {
                    cur = alpha*cur + val[i];
                    vv  = beta*vv + cur;
                    bool s = (vv >= 1.f);
                    u64 bal = __ballot(s);
                    if (s) vv = 0.f;
                    if (l == t && t < ti) myw = bal;
                }
                if (l < TT)
                    pack[((size_t)(tok0+m)*HH + h)*TT + l] = myw;
            }
        } else {
            u16 tmp[4];
            for (int i = 0; i < 4; ++i) {
                const int m  = ph*4 + i;
                const int ti = til[m];
                float vv = 0.f, cur = 0.f, cnt = 0.f;
                #pragma unroll
                for (int t = 0; t < TT; ++t) {
                    cur = alpha*cur + val[i];
                    vv  = beta*vv + cur;
                    bool s = (vv >= 1.f);
                    if (s) { vv = 0.f; if (t < ti) cnt += 1.f; }
                }
                tmp[i] = f2bf(cnt * 0.05f);
            }
            // transposed store: vmbT[ch][tok], 4 tokens = 8B
            *reinterpret_cast<ushort4_t*>(&vmbT[(size_t)tid*BS + tok0 + ph*4]) =
                *reinterpret_cast<ushort4_t*>(tmp);
        }
    }
}

// ===================== Kernel C: popcount scores + softmax + W + PV (MFMA) ===========
// XCD-swizzled: each (b,h) group of 32 tiles lands on one XCD for kpack L2 locality.
__global__ __launch_bounds__(256) void k_attn(
    const u64* __restrict__ qpack, const u64* __restrict__ kpack,
    const u16* __restrict__ vmbT,
    float* __restrict__ Wout, u16* __restrict__ attnb)
{
    __shared__ u64 ql[16][TT];                 // 2.5 KB
    __shared__ __align__(16) u16 CP[16*SS];    // 16 KB
    const int bid  = (int)blockIdx.x;
    const int orig = (bid & 7) * 128 + (bid >> 3);   // bijective for 1024 = 8*128
    const int tid  = threadIdx.x;
    const int tile = orig & 31;
    const int h    = (orig >> 5) & 3;
    const int b    = orig >> 7;
    const int i0   = tile * 16;
    const int lane = tid & 63, wv = tid >> 6;

    for (int idx = tid; idx < 16*TT; idx += 256) {
        int i = idx / TT, t = idx - i*TT;
        ql[i][t] = qpack[((size_t)(b*SS + i0 + i)*HH + h)*TT + t];
    }

    u64 kr0[TT], kr1[TT];
    {
        const u64* kp0 = &kpack[((size_t)(b*SS + tid      )*HH + h)*TT];
        const u64* kp1 = &kpack[((size_t)(b*SS + tid + 256)*HH + h)*TT];
        #pragma unroll
        for (int t = 0; t < TT; ++t) { kr0[t] = kp0[t]; kr1[t] = kp1[t]; }
    }
    __syncthreads();

    for (int i = 0; i < 16; ++i) {
        int c0 = 0, c1 = 0;
        #pragma unroll
        for (int t = 0; t < TT; ++t) {
            u64 q = ql[i][t];
            c0 += __popcll(q & kr0[t]);
            c1 += __popcll(q & kr1[t]);
        }
        CP[i*SS + tid]       = (u16)c0;
        CP[i*SS + tid + 256] = (u16)c1;
    }
    __syncthreads();

    for (int rr = 0; rr < 4; ++rr) {
        const int i = wv*4 + rr;
        float sv[8];
        float m = -1e30f;
        #pragma unroll
        for (int k2 = 0; k2 < 8; ++k2) {
            sv[k2] = (float)CP[i*SS + lane + 64*k2] * 0.125f;
            m = fmaxf(m, sv[k2]);
        }
        #pragma unroll
        for (int msk = 32; msk >= 1; msk >>= 1) m = fmaxf(m, __shfl_xor(m, msk, 64));
        float sum = 0.f;
        #pragma unroll
        for (int k2 = 0; k2 < 8; ++k2) { sv[k2] = expf(sv[k2] - m); sum += sv[k2]; }
        #pragma unroll
        for (int msk = 32; msk >= 1; msk >>= 1) sum += __shfl_xor(sum, msk, 64);
        float inv = 1.f / sum;
        size_t wbase = ((size_t)((b*HH + h)*SS) + i0 + i) * SS;
        #pragma unroll
        for (int k2 = 0; k2 < 8; ++k2) {
            int j = lane + 64*k2;
            float wval = sv[k2] * inv;
            Wout[wbase + j] = wval;
            CP[(i*SS + j) ^ ((i & 7) << 3)] = f2bf(wval);
        }
    }
    __syncthreads();

    const int n0 = wv * 16;
    const int mr = lane & 15;
    const int g  = lane >> 4;
    float4_t acc = {0.f, 0.f, 0.f, 0.f};
    const u16* vbT = vmbT + (size_t)(h*64 + n0 + mr)*BS + b*SS;
    for (int ks = 0; ks < 16; ++ks) {
        int k = ks*32 + g*8;
        int aidx = (mr*SS + k) ^ ((mr & 7) << 3);
        short8 afrag = *reinterpret_cast<const short8*>(&CP[aidx]);
        short8 bfrag = *reinterpret_cast<const short8*>(vbT + k);
        acc = __builtin_amdgcn_mfma_f32_16x16x32_bf16(afrag, bfrag, acc, 0, 0, 0);
    }
    #pragma unroll
    for (int r = 0; r < 4; ++r) {
        int row = g*4 + r;
        attnb[(size_t)(b*SS + i0 + row)*DD + h*64 + n0 + mr] = f2bf(acc[r]);
    }
}

// ===================== Kernel D: out = attn @ Wo + bo via MFMA bf16 + reg =====
__global__ __launch_bounds__(256) void k_outproj(
    const u16* __restrict__ attnb, const u16* __restrict__ WoT,
    const float* __restrict__ bo, const float* __restrict__ ti,
    float* __restrict__ out)
{
    __shared__ float ps[4];
    const int tid  = threadIdx.x;
    const int tok0 = blockIdx.x * 16;
    const int lane = tid & 63;
    const int wv   = tid >> 6;
    const int mr   = lane & 15;
    const int g    = lane >> 4;

    float4_t acc[4];
    #pragma unroll
    for (int f = 0; f < 4; ++f) acc[f] = (float4_t){0.f, 0.f, 0.f, 0.f};

    const size_t arow = (size_t)(tok0 + mr)*DD + g*8;
    #pragma unroll 4
    for (int ks = 0; ks < 8; ++ks) {
        const int k = ks*32;
        short8 a = *reinterpret_cast<const short8*>(&attnb[arow + k]);
        #pragma unroll
        for (int f = 0; f < 4; ++f) {
            const size_t brow = (size_t)(wv*64 + f*16 + mr)*DD + k + g*8;
            short8 b = *reinterpret_cast<const short8*>(&WoT[brow]);
            acc[f] = __builtin_amdgcn_mfma_f32_16x16x32_bf16(a, b, acc[f], 0, 0, 0);
        }
    }
    #pragma unroll
    for (int f = 0; f < 4; ++f) {
        const int col = wv*64 + f*16 + mr;
        const float bb = bo[col];
        #pragma unroll
        for (int r = 0; r < 4; ++r)
            out[(size_t)(tok0 + g*4 + r)*DD + col] = acc[f][r] + bb;
    }

    if (blockIdx.x == 0) {
        float s = 0.f;
        for (int m = 0; m < 16; ++m) s += ti[m*256 + tid];
        #pragma unroll
        for (int msk = 32; msk >= 1; msk >>= 1) s += __shfl_xor(s, msk, 64);
        if ((tid & 63) == 0) ps[tid >> 6] = s;
        __syncthreads();
        if (tid == 0) out[REG_OFF] = 1e-3f * (ps[0]+ps[1]+ps[2]+ps[3]) / 4096.f;
    }
}

extern "C" void kernel_launch(void* const* d_in, const int* in_sizes, int n_in,
                              void* d_out, int out_size, void* d_ws, size_t ws_size,
                              hipStream_t stream)
{
    (void)in_sizes; (void)n_in; (void)out_size; (void)ws_size;
    const float* x   = (const float*)d_in[0];
    const float* Wq  = (const float*)d_in[1];
    const float* Wk  = (const float*)d_in[2];
    const float* Wv  = (const float*)d_in[3];
    const float* Wo  = (const float*)d_in[4];
    const float* bo  = (const float*)d_in[5];
    const float* Wg1 = (const float*)d_in[6];
    const float* bg1 = (const float*)d_in[7];
    const float* Wg2 = (const float*)d_in[8];
    const float* bg2 = (const float*)d_in[9];
    const float* aq  = (const float*)d_in[10];
    const float* bq  = (const float*)d_in[11];
    const float* ak  = (const float*)d_in[12];
    const float* bk  = (const float*)d_in[13];
    const float* av  = (const float*)d_in[14];
    const float* bv  = (const float*)d_in[15];
    float* out = (float*)d_out;

    u64* qp    = (u64*)d_ws;                       // 2.62 MB
    u64* kp    = qp + (size_t)BS*HH*TT;            // 2.62 MB
    u16* vmbT  = (u16*)(kp + (size_t)BS*HH*TT);    // 2 MB
    u16* attnb = vmbT + (size_t)BS*DD;             // 2 MB
    u16* WoT   = attnb + (size_t)BS*DD;            // 128 KB

    k_gate<<<1024, 256, 0, stream>>>(x, Wg1, bg1, Wg2, bg2, out + TI_OFF);
    k_prep_wo<<<32, 256, 0, stream>>>(Wo, WoT);
    dim3 gproj(512, 3);
    k_proj_lif<<<gproj, 256, 0, stream>>>(x, Wq, Wk, Wv,
        aq, bq, ak, bk, av, bv, out + TI_OFF, qp, kp, vmbT);
    k_attn<<<1024, 256, 0, stream>>>(qp, kp, vmbT, out + W_OFF, attnb);
    k_outproj<<<256, 256, 0, stream>>>(attnb, WoT, bo, out + TI_OFF, out);
}